// Round 6
// baseline (450.483 us; speedup 1.0000x reference)
//
#include <hip/hip_runtime.h>
#include <cmath>

#define B_ 32
#define S_ 1024
#define D_ 256
#define K_ 1024
#define N_ (B_*S_)

// ---- output layout (float elements) ----
#define O_Q     0
#define O_LOSS  8388608
#define O_PERP  8388609
#define O_IDX   8388610
#define O_NW    8421378
#define O_NEW   8683522
#define O_NCS   8945666

// ---- workspace layout (bytes) ----
#define OFF_FH    0ull          // 16777216
#define OFF_FL    16777216ull   // 16777216
#define OFF_WH    33554432ull   // 524288
#define OFF_WL    34078720ull   // 524288
#define OFF_BW    34603008ull   // K*8
#define OFF_BWF   34611200ull   // K*4
#define OFF_SAMP  34615296ull   // N*8
#define OFF_IDXF  34877440ull   // N*4
#define OFF_ENC   35008512ull   // N*4
#define OFF_CNT   35139584ull   // K*4   (zeroed)
#define OFF_SLOWC 35143680ull   // 64    (zeroed, same memset)
#define OFF_SLOWL 35143744ull   // N*4
#define OFF_LOSSP 35274816ull   // N*8
#define OFF_ROWL  35536960ull   // N*4
#define OFF_ST    35668032ull   // (K+1)*4
#define OFF_POS   35672192ull   // K*4
#define OFF_CSF   35676288ull   // K*4

#define MARGIN 1e-5f

typedef __bf16 bf16x8 __attribute__((ext_vector_type(8)));
typedef float  f32x4  __attribute__((ext_vector_type(4)));

// offset arg must be a literal at Sema time -> fold k-offset into gp instead.
#define GL16(gp, lp) __builtin_amdgcn_global_load_lds( \
    (const __attribute__((address_space(1))) unsigned int*)(const void*)(gp), \
    (__attribute__((address_space(3))) unsigned int*)(void*)(lp), 16, 0, 0)

// ---------------- LN -> bf16 hi/lo split -------------
__global__ void k_ln(const float* __restrict__ x, const float* __restrict__ gam,
                     const float* __restrict__ bet,
                     __bf16* __restrict__ fh, __bf16* __restrict__ fl) {
    int lane = threadIdx.x & 63, wv = threadIdx.x >> 6;
    int n = blockIdx.x * 4 + wv;
    const float* row = x + (size_t)n * D_;
    double xv[4], gv[4], bv[4];
#pragma unroll
    for (int i = 0; i < 4; i++) {
        int d = lane + 64 * i;
        xv[i] = row[d]; gv[i] = gam[d]; bv[i] = bet[d];
    }
    double s = xv[0] + xv[1] + xv[2] + xv[3];
    for (int m = 32; m > 0; m >>= 1) s += __shfl_xor(s, m, 64);
    double mu = s / 256.0, vs = 0.0;
#pragma unroll
    for (int i = 0; i < 4; i++) { double c = xv[i] - mu; vs += c * c; }
    for (int m = 32; m > 0; m >>= 1) vs += __shfl_xor(vs, m, 64);
    double inv = 1.0 / sqrt(vs / 256.0 + 1e-5);
#pragma unroll
    for (int i = 0; i < 4; i++) {
        int d = lane + 64 * i;
        float ff = (float)((xv[i] - mu) * inv * gv[i] + bv[i]);
        __bf16 h = (__bf16)ff;
        fh[(size_t)n * D_ + d] = h;
        fl[(size_t)n * D_ + d] = (__bf16)(ff - (float)h);
    }
}

// ---------------- ||w||^2 (f64) + bf16 hi/lo of w -------------
__global__ void k_bw(const float* __restrict__ w, double* __restrict__ Bw,
                     float* __restrict__ Bwf,
                     __bf16* __restrict__ wh, __bf16* __restrict__ wl) {
    int lane = threadIdx.x & 63, wv = threadIdx.x >> 6;
    int k = blockIdx.x * 4 + wv;
    double s = 0.0;
#pragma unroll
    for (int i = 0; i < 4; i++) {
        int d = lane + 64 * i;
        float v = w[(size_t)k * D_ + d];
        s += (double)v * (double)v;
        __bf16 h = (__bf16)v;
        wh[(size_t)k * D_ + d] = h;
        wl[(size_t)k * D_ + d] = (__bf16)(v - (float)h);
    }
    for (int m = 32; m > 0; m >>= 1) s += __shfl_xor(s, m, 64);
    if (lane == 0) { Bw[k] = s; Bwf[k] = (float)s; }
}

// ---------------- Phase 1: bf16-split MFMA GEMM + fused top-2 -------------
// 512 blocks x 256 thr (4 waves). Block = 128 rows x 512 codes (2 chunk passes
// of 256 codes). Wave w: 128 rows x codes [w*64, w*64+64) => 32 MFMA per ks.
// K = 3 segs x 256 (fh*wh, fh*wl, fl*wh), BK=32, 24 ks per chunk.
// global_load_lds dwordx4 staging, packed double-buffered LDS (48 KB).
__launch_bounds__(256, 2)
__global__ void k_phase1(const __bf16* __restrict__ fh, const __bf16* __restrict__ fl,
                         const __bf16* __restrict__ wh, const __bf16* __restrict__ wl,
                         const float* __restrict__ Bwf, float* __restrict__ pq) {
    __shared__ __align__(16) __bf16 sA[2][128][32];
    __shared__ __align__(16) __bf16 sB[2][256][32];

    const int tid = threadIdx.x;
    const int lane = tid & 63;
    const int w = tid >> 6;        // wave 0..3
    const int l15 = lane & 15;
    const int g = lane >> 4;       // 0..3
    const int row0 = (blockIdx.x >> 1) * 128;
    const int cb = (blockIdx.x & 1) * 512;

    // staging: lane l -> LDS offset l*16B => row base+(l>>2), col (l&3)*8
    const int srow = lane >> 2;
    const int scol = (lane & 3) * 8;
    // A pointers: wave w stages rows [w*32, w*32+32) via 2 loads of 16 rows
    const __bf16* gafh0 = fh + (size_t)(row0 + w * 32 + srow) * 256 + scol;
    const __bf16* gafh1 = gafh0 + 16 * 256;
    const __bf16* gafl0 = fl + (size_t)(row0 + w * 32 + srow) * 256 + scol;
    const __bf16* gafl1 = gafl0 + 16 * 256;

    for (int chunk = 0; chunk < 2; chunk++) {
        const int c0 = cb + chunk * 256;
        // B pointers: wave w stages code-rows [w*64, w*64+64) via 4 loads
        const __bf16* gbwh0 = wh + (size_t)(c0 + w * 64 + srow) * 256 + scol;
        const __bf16* gbwl0 = wl + (size_t)(c0 + w * 64 + srow) * 256 + scol;

        f32x4 acc[8][4];
#pragma unroll
        for (int a = 0; a < 8; a++)
#pragma unroll
            for (int b = 0; b < 4; b++) acc[a][b] = (f32x4){0.f, 0.f, 0.f, 0.f};

        __syncthreads();   // protect LDS (epilogue of previous chunk) before preload
        // preload ks=0 (seg 0: fh x wh, kk=0)
        GL16(gafh0, &sA[0][w * 32][0]);
        GL16(gafh1, &sA[0][w * 32 + 16][0]);
        GL16(gbwh0,         &sB[0][w * 64][0]);
        GL16(gbwh0 + 4096,  &sB[0][w * 64 + 16][0]);
        GL16(gbwh0 + 8192,  &sB[0][w * 64 + 32][0]);
        GL16(gbwh0 + 12288, &sB[0][w * 64 + 48][0]);

#pragma unroll
        for (int ks = 0; ks < 24; ks++) {
            __syncthreads();   // barrier drain => buf[cur] staging complete
            if (ks < 23) {
                const int k2 = ks + 1;
                const int buf = k2 & 1;
                const int eoff = (k2 & 7) * 32;   // element offset within segment
                const __bf16* ga0 = ((k2 >= 16) ? gafl0 : gafh0) + eoff;
                const __bf16* ga1 = ((k2 >= 16) ? gafl1 : gafh1) + eoff;
                const __bf16* gb = ((k2 >= 8 && k2 < 16) ? gbwl0 : gbwh0) + eoff;
                GL16(ga0, &sA[buf][w * 32][0]);
                GL16(ga1, &sA[buf][w * 32 + 16][0]);
                GL16(gb,         &sB[buf][w * 64][0]);
                GL16(gb + 4096,  &sB[buf][w * 64 + 16][0]);
                GL16(gb + 8192,  &sB[buf][w * 64 + 32][0]);
                GL16(gb + 12288, &sB[buf][w * 64 + 48][0]);
            }
            const int cur = ks & 1;
            bf16x8 bfr[4];
#pragma unroll
            for (int fc = 0; fc < 4; fc++)
                bfr[fc] = *(const bf16x8*)&sB[cur][w * 64 + fc * 16 + l15][g * 8];
#pragma unroll
            for (int fr = 0; fr < 8; fr++) {
                bf16x8 af = *(const bf16x8*)&sA[cur][fr * 16 + l15][g * 8];
#pragma unroll
                for (int fc = 0; fc < 4; fc++)
                    acc[fr][fc] = __builtin_amdgcn_mfma_f32_16x16x32_bf16(
                        af, bfr[fc], acc[fr][fc], 0, 0, 0);
            }
        }
        __syncthreads();   // all buf reads done before red (in sB[0]) is written

        // epilogue: s = Bw - 2P, top-2 per row over this wave's 64 codes
        float bwv[4];
#pragma unroll
        for (int fc = 0; fc < 4; fc++) bwv[fc] = Bwf[c0 + w * 64 + fc * 16 + l15];
        float* red = (float*)&sB[0][0][0];   // 4 waves x 128 rows x 3 = 6 KB
#pragma unroll
        for (int fr = 0; fr < 8; fr++) {
#pragma unroll
            for (int r = 0; r < 4; r++) {
                float m1 = 3e38f, m2 = 3e38f; int c1 = 0x7fffffff;
#pragma unroll
                for (int fc = 0; fc < 4; fc++) {
                    float sv = fmaf(-2.0f, acc[fr][fc][r], bwv[fc]);
                    int c = c0 + w * 64 + fc * 16 + l15;
                    if (sv < m1 || (sv == m1 && c < c1)) { m2 = m1; m1 = sv; c1 = c; }
                    else if (sv < m2) m2 = sv;
                }
#pragma unroll
                for (int msk = 1; msk <= 8; msk <<= 1) {
                    float om1 = __shfl_xor(m1, msk, 64);
                    float om2 = __shfl_xor(m2, msk, 64);
                    int   oc  = __shfl_xor(c1, msk, 64);
                    if (om1 < m1 || (om1 == m1 && oc < c1)) {
                        m2 = (m1 < om2) ? m1 : om2; m1 = om1; c1 = oc;
                    } else {
                        m2 = (om1 < m2) ? om1 : m2;
                    }
                }
                if (l15 == 0) {
                    int rl = fr * 16 + g * 4 + r;
                    int base = (w * 128 + rl) * 3;
                    red[base] = m1; red[base + 1] = m2; ((int*)red)[base + 2] = c1;
                }
            }
        }
        __syncthreads();
        if (tid < 128) {
            float M1 = 3e38f, M2 = 3e38f; int C1 = 0x7fffffff;
            for (int wv = 0; wv < 4; wv++) {   // ascending code order => tie-break OK
                int base = (wv * 128 + tid) * 3;
                float m1 = red[base], m2 = red[base + 1]; int c = ((int*)red)[base + 2];
                if (m1 < M1 || (m1 == M1 && c < C1)) {
                    M2 = (M1 < m2) ? M1 : m2; M1 = m1; C1 = c;
                } else {
                    M2 = (m1 < M2) ? m1 : M2;
                }
            }
            int chunkIdx = (blockIdx.x & 1) * 2 + chunk;
            pq[chunkIdx * N_ + row0 + tid] = M1;                    // pm1
            pq[4 * N_ + chunkIdx * N_ + row0 + tid] = M2;           // pm2
            ((int*)pq)[8 * N_ + chunkIdx * N_ + row0 + tid] = C1;   // pc1
        }
    }
}

// ---------------- Phase 2: merge 4 chunk-partials + exact f64 verify ----
__global__ void k_phase2(const float* __restrict__ x, const float* __restrict__ gam,
                         const float* __restrict__ bet, const float* __restrict__ w,
                         const double* __restrict__ Bw, const float* __restrict__ pq,
                         double* __restrict__ sampled, int* __restrict__ idxf,
                         unsigned* __restrict__ slowC, int* __restrict__ slowL) {
    int lane = threadIdx.x & 63, wv = threadIdx.x >> 6;
    int n = blockIdx.x * 4 + wv;
    const float* pm1 = pq;
    const float* pm2 = pq + 4 * N_;
    const int*   pc1 = (const int*)pq + 8 * N_;
    float M1 = 3e38f, M2 = 3e38f; int C1 = 0x7fffffff;
#pragma unroll
    for (int c = 0; c < 4; c++) {
        float m1 = pm1[c * N_ + n], m2 = pm2[c * N_ + n]; int cc = pc1[c * N_ + n];
        if (m1 < M1 || (m1 == M1 && cc < C1)) {
            M2 = (M1 < m2) ? M1 : m2; M1 = m1; C1 = cc;
        } else {
            M2 = (m1 < M2) ? m1 : M2;
        }
    }
    if (M2 - M1 <= MARGIN) {
        if (lane == 0) { unsigned p = atomicAdd(slowC, 1u); slowL[p] = n; }
        return;
    }
    const float* row = x + (size_t)n * D_;
    double xv[4], gv[4], bv[4];
#pragma unroll
    for (int i = 0; i < 4; i++) {
        int d = lane + 64 * i;
        xv[i] = row[d]; gv[i] = gam[d]; bv[i] = bet[d];
    }
    double s = xv[0] + xv[1] + xv[2] + xv[3];
    for (int m = 32; m > 0; m >>= 1) s += __shfl_xor(s, m, 64);
    double mu = s / 256.0, vs = 0.0;
#pragma unroll
    for (int i = 0; i < 4; i++) { double c = xv[i] - mu; vs += c * c; }
    for (int m = 32; m > 0; m >>= 1) vs += __shfl_xor(vs, m, 64);
    double inv = 1.0 / sqrt(vs / 256.0 + 1e-5);
    double f[4], A = 0.0;
#pragma unroll
    for (int i = 0; i < 4; i++) {
        f[i] = (xv[i] - mu) * inv * gv[i] + bv[i];
        A += f[i] * f[i];
    }
    for (int m = 32; m > 0; m >>= 1) A += __shfl_xor(A, m, 64);

    const float* wr_ = w + (size_t)C1 * D_;
    double ss = 0.0;
#pragma unroll
    for (int i = 0; i < 4; i++) ss += f[i] * (double)wr_[lane + 64 * i];
    for (int m = 32; m > 0; m >>= 1) ss += __shfl_xor(ss, m, 64);
    if (lane == 0) { sampled[n] = (A + Bw[C1]) - 2.0 * ss; idxf[n] = C1; }
}

// ---------------- Slow rows: compacted exact f64 full scan -------------
__launch_bounds__(256)
__global__ void k_slow(const float* __restrict__ x, const float* __restrict__ gam,
                       const float* __restrict__ bet, const float* __restrict__ w,
                       const double* __restrict__ Bw,
                       const int* __restrict__ slowL, const unsigned* __restrict__ slowC,
                       double* __restrict__ sampled, int* __restrict__ idxf) {
    __shared__ double bmS[4];
    __shared__ int    bcS[4];
    int lane = threadIdx.x & 63, wv = threadIdx.x >> 6;
    int cnt = (int)*slowC;
    for (int it = blockIdx.x; it < cnt; it += gridDim.x) {
        int n = slowL[it];
        const float* row = x + (size_t)n * D_;
        float4 xv4 = *(const float4*)(row + lane * 4);
        float4 gv4 = *(const float4*)(gam + lane * 4);
        float4 bv4 = *(const float4*)(bet + lane * 4);
        double xv[4] = {(double)xv4.x, (double)xv4.y, (double)xv4.z, (double)xv4.w};
        double gv[4] = {(double)gv4.x, (double)gv4.y, (double)gv4.z, (double)gv4.w};
        double bv[4] = {(double)bv4.x, (double)bv4.y, (double)bv4.z, (double)bv4.w};
        double s = xv[0] + xv[1] + xv[2] + xv[3];
        for (int m = 32; m > 0; m >>= 1) s += __shfl_xor(s, m, 64);
        double mu = s / 256.0, vs = 0.0;
#pragma unroll
        for (int i = 0; i < 4; i++) { double c = xv[i] - mu; vs += c * c; }
        for (int m = 32; m > 0; m >>= 1) vs += __shfl_xor(vs, m, 64);
        double inv = 1.0 / sqrt(vs / 256.0 + 1e-5);
        double f[4], A = 0.0;
#pragma unroll
        for (int i = 0; i < 4; i++) {
            f[i] = (xv[i] - mu) * inv * gv[i] + bv[i];
            A += f[i] * f[i];
        }
        for (int m = 32; m > 0; m >>= 1) A += __shfl_xor(A, m, 64);

        double bm = 1.0e300; int bc = 0x7fffffff;
        int cbase = wv * 256;
#pragma unroll 2
        for (int c = cbase; c < cbase + 256; c++) {
            float4 w4 = *(const float4*)(w + (size_t)c * D_ + lane * 4);
            double ss = f[0] * (double)w4.x + f[1] * (double)w4.y
                      + f[2] * (double)w4.z + f[3] * (double)w4.w;
            for (int m = 32; m > 0; m >>= 1) ss += __shfl_xor(ss, m, 64);
            double dist = (A + Bw[c]) - 2.0 * ss;
            if (dist < bm) { bm = dist; bc = c; }
        }
        if (lane == 0) { bmS[wv] = bm; bcS[wv] = bc; }
        __syncthreads();
        if (threadIdx.x == 0) {
            double M = bmS[0]; int C = bcS[0];
            for (int i = 1; i < 4; i++)
                if (bmS[i] < M || (bmS[i] == M && bcS[i] < C)) { M = bmS[i]; C = bcS[i]; }
            sampled[n] = M; idxf[n] = C;
        }
        __syncthreads();
    }
}

// ---------------- stable argsort per batch row + enc gather -------------
__launch_bounds__(1024)
__global__ void k_sort(const double* __restrict__ sampled, const int* __restrict__ idxf,
                       int* __restrict__ enc) {
    __shared__ double val[1024];
    __shared__ int    sid[1024];
    int b = blockIdx.x, t = threadIdx.x;
    val[t] = sampled[(size_t)b * S_ + t];
    sid[t] = t;
    __syncthreads();
    for (int k = 2; k <= 1024; k <<= 1) {
        for (int j = k >> 1; j > 0; j >>= 1) {
            int p = t ^ j;
            if (p > t) {
                double v0 = val[t], v1 = val[p];
                int i0 = sid[t], i1 = sid[p];
                bool gtv = (v0 > v1) || (v0 == v1 && i0 > i1);
                bool asc = ((t & k) == 0);
                if (asc ? gtv : !gtv) {
                    val[t] = v1; val[p] = v0; sid[t] = i1; sid[p] = i0;
                }
            }
            __syncthreads();
        }
    }
    enc[(size_t)b * S_ + t] = idxf[sid[t]];   // faithful reference flat-index bug
}

// ---------------- gather: quantized out, idx out, counts, per-row loss -------------
__global__ void k_gather(const float* __restrict__ x, const float* __restrict__ w,
                         const int* __restrict__ enc, float* __restrict__ out,
                         unsigned* __restrict__ cnt, double* __restrict__ lossP) {
    int lane = threadIdx.x & 63, wv = threadIdx.x >> 6;
    int n = blockIdx.x * 4 + wv;
    int e = enc[n];
    const float* wr_ = w + (size_t)e * D_;
    const float* xr = x + (size_t)n * D_;
    float* qr = out + O_Q + (size_t)n * D_;
    double ls = 0.0;
#pragma unroll
    for (int i = 0; i < 4; i++) {
        int d = lane + 64 * i;
        float q = wr_[d], xv = xr[d];
        qr[d] = q;
        double df = (double)q - (double)xv;
        ls += df * df;
    }
    for (int m = 32; m > 0; m >>= 1) ls += __shfl_xor(ls, m, 64);
    if (lane == 0) {
        lossP[n] = ls;
        out[O_IDX + n] = (float)e;
        atomicAdd(&cnt[e], 1u);
    }
}

// ---------------- finalize (+ fused prefix scan for CSR) -------------
__launch_bounds__(1024)
__global__ void k_final(const unsigned* __restrict__ cnt, const float* __restrict__ ema_cs,
                        const double* __restrict__ lossP, float* __restrict__ out,
                        float* __restrict__ csf, int* __restrict__ starts,
                        int* __restrict__ pos) {
    __shared__ double red[1024];
    __shared__ int sc[1024];
    int t = threadIdx.x;
    int cv = (int)cnt[t];
    float cf = (float)cv;
    float cs0 = 0.99f * ema_cs[t] + 0.01f * cf;
    red[t] = (double)cs0;
    sc[t] = cv;
    __syncthreads();
    for (int s = 512; s > 0; s >>= 1) { if (t < s) red[t] += red[t + s]; __syncthreads(); }
    double ntot = red[0];
    __syncthreads();
    double c2 = ((double)cs0 + 1e-5) / (ntot + 1024.0 * 1e-5) * ntot;
    out[O_NCS + t] = (float)c2;
    csf[t] = (float)c2;
    double p = (double)cf / 32768.0;
    red[t] = -p * log(p + 1e-10);
    __syncthreads();
    for (int s = 512; s > 0; s >>= 1) { if (t < s) red[t] += red[t + s]; __syncthreads(); }
    double ent = red[0];
    __syncthreads();
    double ls = 0.0;
    for (int i = 0; i < 32; i++) ls += lossP[t + 1024 * i];
    red[t] = ls;
    __syncthreads();
    for (int s = 512; s > 0; s >>= 1) { if (t < s) red[t] += red[t + s]; __syncthreads(); }
    if (t == 0) {
        out[O_PERP] = (float)exp(ent);
        out[O_LOSS] = (float)(1.25 * red[0] / 8388608.0);
    }
    // prefix scan of counts -> starts/pos
    for (int off = 1; off < 1024; off <<= 1) {
        int add = (t >= off) ? sc[t - off] : 0;
        __syncthreads();
        sc[t] += add;
        __syncthreads();
    }
    int excl = sc[t] - cv;
    starts[t] = excl;
    pos[t] = excl;
    if (t == 1023) starts[1024] = sc[t];
}

__global__ void k_fill(const int* __restrict__ enc, int* __restrict__ pos,
                       int* __restrict__ rowl) {
    int n = blockIdx.x * 256 + threadIdx.x;
    int p = atomicAdd(&pos[enc[n]], 1);
    rowl[p] = n;
}

// ---------------- dw gather-sum + EMA + new_weight -------------
__global__ void k_dwsum(const float* __restrict__ x, const float* __restrict__ ema_w,
                        const int* __restrict__ rowl, const int* __restrict__ starts,
                        const float* __restrict__ csf, float* __restrict__ out) {
    int k = blockIdx.x, d = threadIdx.x;
    int s0 = starts[k], s1 = starts[k + 1];
    float acc = 0.0f;
    for (int i = s0; i < s1; i++) {
        int rr = rowl[i];
        acc += x[(size_t)rr * D_ + d];
    }
    size_t idx = (size_t)k * D_ + d;
    float ne = 0.99f * ema_w[idx] + 0.01f * acc;
    out[O_NEW + idx] = ne;
    out[O_NW + idx] = ne / csf[k];
}

extern "C" void kernel_launch(void* const* d_in, const int* in_sizes, int n_in,
                              void* d_out, int out_size, void* d_ws, size_t ws_size,
                              hipStream_t stream) {
    (void)in_sizes; (void)n_in; (void)out_size; (void)ws_size;
    const float* x      = (const float*)d_in[0];
    const float* w      = (const float*)d_in[1];
    const float* ema_w  = (const float*)d_in[2];
    const float* ema_cs = (const float*)d_in[3];
    const float* g      = (const float*)d_in[4];
    const float* bt     = (const float*)d_in[5];
    float* out = (float*)d_out;
    char* ws = (char*)d_ws;

    __bf16* fh   = (__bf16*)(ws + OFF_FH);
    __bf16* fl   = (__bf16*)(ws + OFF_FL);
    __bf16* wh   = (__bf16*)(ws + OFF_WH);
    __bf16* wl   = (__bf16*)(ws + OFF_WL);
    double* Bw   = (double*)(ws + OFF_BW);
    float*  Bwf  = (float*)(ws + OFF_BWF);
    double* samp = (double*)(ws + OFF_SAMP);
    int*    idxf = (int*)(ws + OFF_IDXF);
    int*    enc  = (int*)(ws + OFF_ENC);
    unsigned* cnt = (unsigned*)(ws + OFF_CNT);
    unsigned* slowC = (unsigned*)(ws + OFF_SLOWC);
    int*    slowL = (int*)(ws + OFF_SLOWL);
    double* lossP = (double*)(ws + OFF_LOSSP);
    int*    rowl = (int*)(ws + OFF_ROWL);
    int*    st   = (int*)(ws + OFF_ST);
    int*    pos  = (int*)(ws + OFF_POS);
    float*  csf  = (float*)(ws + OFF_CSF);

    (void)hipMemsetAsync(ws + OFF_CNT, 0, 4160, stream);   // cnt + slowC

    k_ln<<<N_ / 4, 256, 0, stream>>>(x, g, bt, fh, fl);
    k_bw<<<K_ / 4, 256, 0, stream>>>(w, Bw, Bwf, wh, wl);
    k_phase1<<<512, 256, 0, stream>>>(fh, fl, wh, wl, Bwf, out);  // partials in out-Q (dead region)
    k_phase2<<<N_ / 4, 256, 0, stream>>>(x, g, bt, w, Bw, out, samp, idxf, slowC, slowL);
    k_slow<<<256, 256, 0, stream>>>(x, g, bt, w, Bw, slowL, slowC, samp, idxf);
    k_sort<<<B_, 1024, 0, stream>>>(samp, idxf, enc);
    k_gather<<<N_ / 4, 256, 0, stream>>>(x, w, enc, out, cnt, lossP);
    k_final<<<1, 1024, 0, stream>>>(cnt, ema_cs, lossP, out, csf, st, pos);
    k_fill<<<N_ / 256, 256, 0, stream>>>(enc, pos, rowl);
    k_dwsum<<<K_, 256, 0, stream>>>(x, ema_w, rowl, st, csf, out);
}